// Round 2
// baseline (459.014 us; speedup 1.0000x reference)
//
#include <hip/hip_runtime.h>

typedef __bf16 bf16x8 __attribute__((ext_vector_type(8)));
typedef float  f32x4  __attribute__((ext_vector_type(4)));
typedef float  fvec4  __attribute__((ext_vector_type(4)));

#define NSPEC 8
#define NB    65536
#define NF    256

// ---------------------------------------------------------------------------
// Prologue: W[l][s][in][out] f32  ->  WT[l][s][out][in] bf16   (3 MB in d_ws)
// ---------------------------------------------------------------------------
__global__ __launch_bounds__(256) void wconv_kernel(
    const float* __restrict__ W1, const float* __restrict__ W2,
    const float* __restrict__ W3, __bf16* __restrict__ WT)
{
    __shared__ float tile[32][33];
    int bid = blockIdx.x;
    int l   = bid >> 9;        // 512 blocks per layer (8 species * 64 tiles)
    int rem = bid & 511;
    int s   = rem >> 6;
    int tt  = rem & 63;
    int ti  = tt >> 3, tj = tt & 7;     // 32x32 tile coords: ti=in, tj=out
    const float* W   = (l == 0) ? W1 : (l == 1) ? W2 : W3;
    const float* ibs = W + (size_t)s * 65536;
    int c  = threadIdx.x & 31;
    int r0 = threadIdx.x >> 5;          // 0..7
#pragma unroll
    for (int k = 0; k < 4; ++k) {
        int r = r0 + k * 8;
        tile[r][c] = ibs[(ti * 32 + r) * 256 + tj * 32 + c];
    }
    __syncthreads();
    __bf16* obs = WT + ((size_t)(l * 8 + s)) * 65536;
#pragma unroll
    for (int k = 0; k < 4; ++k) {
        int r = r0 + k * 8;             // out-row within tile
        obs[(tj * 32 + r) * 256 + ti * 32 + c] = (__bf16)tile[c][r];
    }
}

// ---------------------------------------------------------------------------
// Fused MLP: per block 64 batch rows, loop species, 3 MFMA layers + dot layer.
// Swapped operands: D[v][batch] = WT(A) x actT(B). act LDS XOR-swizzled.
// ---------------------------------------------------------------------------
__global__ __launch_bounds__(512, 4) void mlp_kernel(
    const float* __restrict__ bIn, const float* __restrict__ b1,
    const float* __restrict__ b2,  const float* __restrict__ b3,
    const float* __restrict__ W4,  const float* __restrict__ b4,
    const __bf16* __restrict__ WT, float* __restrict__ out)
{
    __shared__ __align__(16) __bf16 actA[64 * 256];   // 32 KB
    __shared__ __align__(16) __bf16 actB[64 * 256];   // 32 KB
    char* const pA = (char*)actA;
    char* const pB = (char*)actB;

    const int t    = threadIdx.x;
    const int lane = t & 63;
    const int wave = t >> 6;          // 0..7, owns v-range [wave*32, wave*32+32)
    const int l15  = lane & 15;
    const int g    = lane >> 4;       // 0..3
    const int vw   = wave * 32;
    const int row0 = blockIdx.x * 64;
    const int swzB = (l15 & 7) << 4;  // bank swizzle for act reads / D writes

    // layer-4 mapping: 8 threads per row, 32 u's each
    const int r4   = t >> 3;          // 0..63
    const int u0   = (t & 7) * 32;
    const int swz4 = (r4 & 7) << 4;

    float Asum = 0.f, bsum = 0.f;

    for (int s = 0; s < NSPEC; ++s) {
        // ---- stage b[s][row0..row0+63][:] fp32 -> bf16 into actA (swizzled)
        const float* src = bIn + ((size_t)s * NB + row0) * NF;
#pragma unroll
        for (int it = 0; it < 8; ++it) {
            int flat = it * 2048 + t * 4;
            int r = flat >> 8;
            int f = flat & 255;
            fvec4 v = __builtin_nontemporal_load((const fvec4*)(src + flat));
            union { __bf16 h[4]; unsigned long long q; } pk;
            pk.h[0] = (__bf16)v[0]; pk.h[1] = (__bf16)v[1];
            pk.h[2] = (__bf16)v[2]; pk.h[3] = (__bf16)v[3];
            *(unsigned long long*)(pA + r * 512 + ((f * 2) ^ ((r & 7) << 4))) = pk.q;
        }
        __syncthreads();

        const char* sbuf = pA;
        char*       dbuf = pB;
        for (int l = 0; l < 3; ++l) {
            const __bf16* wt = WT + ((size_t)(l * 8 + s) << 16);
            const float*  bl = (l == 0 ? b1 : l == 1 ? b2 : b3) + s * 256;

            // init acc with bias (depends on v only)
            f32x4 acc[2][4];
#pragma unroll
            for (int m = 0; m < 2; ++m) {
                f32x4 bv;
#pragma unroll
                for (int j = 0; j < 4; ++j) bv[j] = bl[vw + m * 16 + g * 4 + j];
#pragma unroll
                for (int n = 0; n < 4; ++n) acc[m][n] = bv;
            }

#pragma unroll
            for (int ks = 0; ks < 8; ++ks) {
                bf16x8 af[2], bfr[4];
#pragma unroll
                for (int m = 0; m < 2; ++m)
                    af[m] = *(const bf16x8*)(wt + (vw + m * 16 + l15) * 256 + ks * 32 + g * 8);
#pragma unroll
                for (int n = 0; n < 4; ++n)
                    bfr[n] = *(const bf16x8*)(sbuf + (n * 16 + l15) * 512 + ((ks * 64 + g * 16) ^ swzB));
#pragma unroll
                for (int m = 0; m < 2; ++m)
#pragma unroll
                    for (int n = 0; n < 4; ++n)
                        acc[m][n] = __builtin_amdgcn_mfma_f32_16x16x32_bf16(af[m], bfr[n], acc[m][n], 0, 0, 0);
            }

            // epilogue: leaky, cvt to bf16, packed 8B write (4 consecutive v)
#pragma unroll
            for (int m = 0; m < 2; ++m) {
                int vbyte = (vw + m * 16 + g * 4) * 2;
#pragma unroll
                for (int n = 0; n < 4; ++n) {
                    union { __bf16 h[4]; unsigned long long q; } pk;
#pragma unroll
                    for (int j = 0; j < 4; ++j) {
                        float x = acc[m][n][j];
                        x = (x >= 0.f) ? x : 0.1f * x;
                        pk.h[j] = (__bf16)x;
                    }
                    *(unsigned long long*)(dbuf + (n * 16 + l15) * 512 + (vbyte ^ swzB)) = pk.q;
                }
            }
            __syncthreads();
            const char* tmp = sbuf; sbuf = dbuf; dbuf = (char*)tmp;
        }

        // ---- layer 4: A_s[row] = dot(act3[row], w4[s]) ; accumulate over s
        const float* w4s = W4 + s * 256 + u0;
        float part = 0.f;
#pragma unroll
        for (int i = 0; i < 4; ++i) {
            bf16x8 x = *(const bf16x8*)(sbuf + r4 * 512 + (((u0 + i * 8) * 2) ^ swz4));
            fvec4 wlo = *(const fvec4*)(w4s + i * 8);
            fvec4 whi = *(const fvec4*)(w4s + i * 8 + 4);
            part += (float)x[0] * wlo[0] + (float)x[1] * wlo[1] +
                    (float)x[2] * wlo[2] + (float)x[3] * wlo[3] +
                    (float)x[4] * whi[0] + (float)x[5] * whi[1] +
                    (float)x[6] * whi[2] + (float)x[7] * whi[3];
        }
        Asum += part;
        bsum += b4[s];
        // no extra barrier: next stage writes actA, L4 reads actB; the
        // stage-barrier below orders everything else.
    }

    float tot = Asum;
    tot += __shfl_xor(tot, 1);
    tot += __shfl_xor(tot, 2);
    tot += __shfl_xor(tot, 4);
    tot += bsum;
    float y = 1.f / (1.f + __expf(-tot));
    if ((t & 7) == 0) out[row0 + r4] = y;
}

extern "C" void kernel_launch(void* const* d_in, const int* in_sizes, int n_in,
                              void* d_out, int out_size, void* d_ws, size_t ws_size,
                              hipStream_t stream)
{
    const float* bIn = (const float*)d_in[0];
    const float* W1  = (const float*)d_in[1];
    const float* b1  = (const float*)d_in[2];
    const float* W2  = (const float*)d_in[3];
    const float* b2  = (const float*)d_in[4];
    const float* W3  = (const float*)d_in[5];
    const float* b3  = (const float*)d_in[6];
    const float* W4  = (const float*)d_in[7];
    const float* b4  = (const float*)d_in[8];
    __bf16* WT = (__bf16*)d_ws;   // 3 * 8 * 256 * 256 * 2B = 3 MB

    wconv_kernel<<<1536, 256, 0, stream>>>(W1, W2, W3, WT);
    mlp_kernel<<<1024, 512, 0, stream>>>(bIn, b1, b2, b3, W4, b4, WT, (float*)d_out);
}

// Round 3
// 457.203 us; speedup vs baseline: 1.0040x; 1.0040x over previous
//
#include <hip/hip_runtime.h>

typedef __bf16 bf16x8 __attribute__((ext_vector_type(8)));
typedef float  f32x4  __attribute__((ext_vector_type(4)));
typedef float  fvec4  __attribute__((ext_vector_type(4)));

#define NSPEC 8
#define NB    65536
#define NF    256

// ---------------------------------------------------------------------------
// Prologue: W[l][s][in][out] f32  ->  WT[l][s][out][in] bf16   (3 MB in d_ws)
// ---------------------------------------------------------------------------
__global__ __launch_bounds__(256) void wconv_kernel(
    const float* __restrict__ W1, const float* __restrict__ W2,
    const float* __restrict__ W3, __bf16* __restrict__ WT)
{
    __shared__ float tile[32][33];
    int bid = blockIdx.x;
    int l   = bid >> 9;        // 512 blocks per layer (8 species * 64 tiles)
    int rem = bid & 511;
    int s   = rem >> 6;
    int tt  = rem & 63;
    int ti  = tt >> 3, tj = tt & 7;     // 32x32 tile coords: ti=in, tj=out
    const float* W   = (l == 0) ? W1 : (l == 1) ? W2 : W3;
    const float* ibs = W + (size_t)s * 65536;
    int c  = threadIdx.x & 31;
    int r0 = threadIdx.x >> 5;          // 0..7
#pragma unroll
    for (int k = 0; k < 4; ++k) {
        int r = r0 + k * 8;
        tile[r][c] = ibs[(ti * 32 + r) * 256 + tj * 32 + c];
    }
    __syncthreads();
    __bf16* obs = WT + ((size_t)(l * 8 + s)) * 65536;
#pragma unroll
    for (int k = 0; k < 4; ++k) {
        int r = r0 + k * 8;             // out-row within tile
        obs[(tj * 32 + r) * 256 + ti * 32 + c] = (__bf16)tile[c][r];
    }
}

// ---------------------------------------------------------------------------
// Fused MLP: per block 64 batch rows, loop species, 3 MFMA layers + dot layer.
// Swapped operands: D[v][batch] = WT(A) x actT(B). act LDS XOR-swizzled
// with the full 4-bit row swizzle ((r&15)<<4) so every 16-lane read group
// hits 16 distinct 16B slots. Weights preloaded per-layer into registers.
// ---------------------------------------------------------------------------
__global__ __launch_bounds__(512, 4) void mlp_kernel(
    const float* __restrict__ bIn, const float* __restrict__ b1,
    const float* __restrict__ b2,  const float* __restrict__ b3,
    const float* __restrict__ W4,  const float* __restrict__ b4,
    const __bf16* __restrict__ WT, float* __restrict__ out)
{
    __shared__ __align__(16) __bf16 actA[64 * 256];   // 32 KB
    __shared__ __align__(16) __bf16 actB[64 * 256];   // 32 KB
    char* const pA = (char*)actA;
    char* const pB = (char*)actB;

    const int t    = threadIdx.x;
    const int lane = t & 63;
    const int wave = t >> 6;          // 0..7, owns v-range [wave*32, wave*32+32)
    const int l15  = lane & 15;
    const int g    = lane >> 4;       // 0..3
    const int vw   = wave * 32;
    const int row0 = blockIdx.x * 64;
    const int swzB = l15 << 4;        // full 4-bit row swizzle for reads/writes

    // layer-4 mapping: 8 threads per row, 32 u's each
    const int r4   = t >> 3;          // 0..63
    const int u0   = (t & 7) * 32;
    const int swz4 = (r4 & 15) << 4;

    float Asum = 0.f, bsum = 0.f;

    for (int s = 0; s < NSPEC; ++s) {
        // ---- stage b[s][row0..row0+63][:] fp32 -> bf16 into actA (swizzled)
        // per wave-iteration: all 64 lanes write one row (contiguous 512B).
        const float* src = bIn + ((size_t)s * NB + row0) * NF;
#pragma unroll
        for (int it = 0; it < 8; ++it) {
            int flat = it * 2048 + t * 4;
            int r = flat >> 8;
            int f = flat & 255;
            fvec4 v = __builtin_nontemporal_load((const fvec4*)(src + flat));
            union { __bf16 h[4]; unsigned long long q; } pk;
            pk.h[0] = (__bf16)v[0]; pk.h[1] = (__bf16)v[1];
            pk.h[2] = (__bf16)v[2]; pk.h[3] = (__bf16)v[3];
            *(unsigned long long*)(pA + r * 512 + ((f * 2) ^ ((r & 15) << 4))) = pk.q;
        }
        __syncthreads();

        const char* sbuf = pA;
        char*       dbuf = pB;
        for (int l = 0; l < 3; ++l) {
            const __bf16* wt = WT + ((size_t)(l * 8 + s) << 16);
            const float*  bl = (l == 0 ? b1 : l == 1 ? b2 : b3) + s * 256;

            // ---- preload the whole layer's A-operand (weights) into regs:
            // 16 fragments x 16B = 64 VGPRs, all loads issued back-to-back.
            bf16x8 wreg[16];
#pragma unroll
            for (int ks = 0; ks < 8; ++ks)
#pragma unroll
                for (int m = 0; m < 2; ++m)
                    wreg[ks * 2 + m] =
                        *(const bf16x8*)(wt + (vw + m * 16 + l15) * 256 + ks * 32 + g * 8);

            // init acc with bias (depends on v only)
            f32x4 acc[2][4];
#pragma unroll
            for (int m = 0; m < 2; ++m) {
                fvec4 bq = *(const fvec4*)(bl + vw + m * 16 + g * 4);
                f32x4 bv; bv[0] = bq[0]; bv[1] = bq[1]; bv[2] = bq[2]; bv[3] = bq[3];
#pragma unroll
                for (int n = 0; n < 4; ++n) acc[m][n] = bv;
            }

#pragma unroll
            for (int ks = 0; ks < 8; ++ks) {
                bf16x8 bfr[4];
#pragma unroll
                for (int n = 0; n < 4; ++n)
                    bfr[n] = *(const bf16x8*)(sbuf + (n * 16 + l15) * 512 + ((ks * 64 + g * 16) ^ swzB));
#pragma unroll
                for (int m = 0; m < 2; ++m)
#pragma unroll
                    for (int n = 0; n < 4; ++n)
                        acc[m][n] = __builtin_amdgcn_mfma_f32_16x16x32_bf16(wreg[ks * 2 + m], bfr[n], acc[m][n], 0, 0, 0);
            }

            // epilogue: leaky, cvt to bf16, packed 8B write (4 consecutive v)
#pragma unroll
            for (int m = 0; m < 2; ++m) {
                int vbyte = (vw + m * 16 + g * 4) * 2;
#pragma unroll
                for (int n = 0; n < 4; ++n) {
                    union { __bf16 h[4]; unsigned long long q; } pk;
#pragma unroll
                    for (int j = 0; j < 4; ++j) {
                        float x = acc[m][n][j];
                        x = (x >= 0.f) ? x : 0.1f * x;
                        pk.h[j] = (__bf16)x;
                    }
                    *(unsigned long long*)(dbuf + (n * 16 + l15) * 512 + (vbyte ^ swzB)) = pk.q;
                }
            }
            __syncthreads();
            const char* tmp = sbuf; sbuf = dbuf; dbuf = (char*)tmp;
        }

        // ---- layer 4: A_s[row] = dot(act3[row], w4[s]) ; accumulate over s
        const float* w4s = W4 + s * 256 + u0;
        float part = 0.f;
#pragma unroll
        for (int i = 0; i < 4; ++i) {
            bf16x8 x = *(const bf16x8*)(sbuf + r4 * 512 + (((u0 + i * 8) * 2) ^ swz4));
            fvec4 wlo = *(const fvec4*)(w4s + i * 8);
            fvec4 whi = *(const fvec4*)(w4s + i * 8 + 4);
            part += (float)x[0] * wlo[0] + (float)x[1] * wlo[1] +
                    (float)x[2] * wlo[2] + (float)x[3] * wlo[3] +
                    (float)x[4] * whi[0] + (float)x[5] * whi[1] +
                    (float)x[6] * whi[2] + (float)x[7] * whi[3];
        }
        Asum += part;
        bsum += b4[s];
        // no extra barrier needed: next stage writes actA, L4 reads actB
        // (last swap left act3 in pB), and the stage barrier orders the rest.
    }

    float tot = Asum;
    tot += __shfl_xor(tot, 1);
    tot += __shfl_xor(tot, 2);
    tot += __shfl_xor(tot, 4);
    tot += bsum;
    float y = 1.f / (1.f + __expf(-tot));
    if ((t & 7) == 0) out[row0 + r4] = y;
}

extern "C" void kernel_launch(void* const* d_in, const int* in_sizes, int n_in,
                              void* d_out, int out_size, void* d_ws, size_t ws_size,
                              hipStream_t stream)
{
    const float* bIn = (const float*)d_in[0];
    const float* W1  = (const float*)d_in[1];
    const float* b1  = (const float*)d_in[2];
    const float* W2  = (const float*)d_in[3];
    const float* b2  = (const float*)d_in[4];
    const float* W3  = (const float*)d_in[5];
    const float* b3  = (const float*)d_in[6];
    const float* W4  = (const float*)d_in[7];
    const float* b4  = (const float*)d_in[8];
    __bf16* WT = (__bf16*)d_ws;   // 3 * 8 * 256 * 256 * 2B = 3 MB

    wconv_kernel<<<1536, 256, 0, stream>>>(W1, W2, W3, WT);
    mlp_kernel<<<1024, 512, 0, stream>>>(bIn, b1, b2, b3, W4, b4, WT, (float*)d_out);
}